// Round 6
// baseline (94.664 us; speedup 1.0000x reference)
//
#include <hip/hip_runtime.h>
#include <hip/hip_bf16.h>
#include <cmath>

typedef unsigned short u16;
typedef __bf16 bf16x8 __attribute__((ext_vector_type(8)));
typedef float  f32x4  __attribute__((ext_vector_type(4)));
typedef float  f4     __attribute__((ext_vector_type(4)));
typedef u16    us4    __attribute__((ext_vector_type(4)));

#define DEVFN __device__ __forceinline__

static constexpr int Bq = 2, Nq = 2048, Eq = 1024;
static constexpr int Mq = Bq * Nq;        // 4096 tokens
static constexpr int CHK = 64;            // attention chunk
static constexpr int NC  = Nq / CHK;      // 32 chunks
static constexpr int BH  = Bq * 16;       // 32

DEVFN u16 f2b(float f) {                  // f32 -> bf16 (RNE), finite inputs
    union { float f; unsigned int u; } x; x.f = f;
    unsigned int r = x.u + 0x7fffu + ((x.u >> 16) & 1u);
    return (u16)(r >> 16);
}
DEVFN float b2f(u16 v) {
    union { unsigned int u; float f; } x; x.u = ((unsigned int)v) << 16; return x.f;
}

DEVFN void gl_lds16(const u16* g, u16* l) {  // async 16B global->LDS (dest: wave base + lane*16)
    __builtin_amdgcn_global_load_lds(
        (const __attribute__((address_space(1))) unsigned int*)(g),
        (__attribute__((address_space(3))) unsigned int*)(l),
        16, 0, 0);
}

// ---------------- all f32 -> bf16 converts in ONE launch ----------------
__global__ __launch_bounds__(256)
void cvt_all_kernel(const float* __restrict__ x,
                    const float* __restrict__ w0, const float* __restrict__ w1,
                    const float* __restrict__ w2, const float* __restrict__ w3,
                    u16* __restrict__ Xb, u16* __restrict__ Wb)
{
    const int blk = blockIdx.x;
    const float* s; u16* d; int i;
    if (blk < 4096) {
        i = blk * 256 + threadIdx.x;  s = x;  d = Xb;
    } else {
        const int wsel = (blk - 4096) >> 10;
        i = ((blk - 4096) & 1023) * 256 + threadIdx.x;
        s = (wsel == 0) ? w0 : (wsel == 1) ? w1 : (wsel == 2) ? w2 : w3;
        d = Wb + (size_t)wsel * (Eq * Eq);
    }
    f4 v = *reinterpret_cast<const f4*>(&s[(size_t)i * 4]);
    us4 p; p[0] = f2b(v[0]); p[1] = f2b(v[1]); p[2] = f2b(v[2]); p[3] = f2b(v[3]);
    *reinterpret_cast<us4*>(&d[(size_t)i * 4]) = p;
}

// ======== ring GEMM: BMx128 tile, 2 waves (64x128 per wave), BK=32, 3-buf ring ========
// MODE 0: fused QKV, BM=128, N=3072 (seg 0=Q elu+1, 1=K elu+1 ->Kb+KbT, 2=V ->VbT)
// MODE 1: O-projection, BM=64, N=1024, f32 output.
// Swizzle: granule slot sigma = s ^ ((row>>1)&3) on BOTH staging source and ds_read
// (involution; 64B rows -> 8 consecutive rows cover all 8 bank-quads, 2-way = free).
template<int MODE>
__global__ __launch_bounds__(128, 2)
void gemm_ring(const u16* __restrict__ X, const u16* __restrict__ W,
               const float* __restrict__ b0, const float* __restrict__ b1,
               const float* __restrict__ b2,
               u16* __restrict__ Qb, u16* __restrict__ Kb, u16* __restrict__ KbT,
               u16* __restrict__ VbT, float* __restrict__ outF)
{
    constexpr int BM   = (MODE == 0) ? 128 : 64;
    constexpr int MI   = BM / 32;              // M-frags per wave (wave rows = BM/2)
    constexpr int AR   = BM / 32;              // A staging rounds (128 granules each)
    constexpr int BUFU = (BM + 128) * 32;      // u16 per ring buffer (A | B)
    constexpr int NT   = 32;                   // K tiles (1024/32)
    __shared__ u16 lds[3 * BUFU];              // 48KB (MODE0) / 36KB (MODE1)

    const int tid = threadIdx.x, wid = tid >> 6, lane = tid & 63;
    const int bid = blockIdx.x;
    // XCD-bijective swizzle (grid 768 / 512, both %8==0)
    const int fid = (MODE == 0) ? ((bid & 7) * 96 + (bid >> 3))
                                : ((bid & 7) * 64 + (bid >> 3));
    const int bx  = (MODE == 0) ? (fid % 24) : (fid & 7);
    const int by  = (MODE == 0) ? (fid / 24) : (fid >> 3);
    const int m0  = by * BM, n0 = bx * 128;
    const int wr  = wid * (BM / 2);
    const int fr  = lane & 15, fq = lane >> 4;

    // staging: granule g = it*128 + tid; row = g>>2, slot = g&3 (slot const per thread,
    // row advances by 32 per round so (row>>1)&3 is const per thread too)
    const int row0 = tid >> 2;
    const int ssw  = ((tid & 3) ^ ((row0 >> 1) & 3)) * 8;   // swizzled source 16B slot
    const u16* gA = X + (size_t)(m0 + row0) * 1024 + ssw;
    const u16* gB = W + (size_t)(n0 + row0) * 1024 + ssw;
    const int dstA = wid * 512;                // + it*1024 (wave-uniform, linear dest)
    const int dstB = BM * 32 + wid * 512;

    // fragment reads: same involution on the read side
    const int fsw = (fq ^ ((fr >> 1) & 3)) << 3;
    int aoff[MI], boff[8];
#pragma unroll
    for (int mi = 0; mi < MI; ++mi) aoff[mi] = (wr + mi * 16 + fr) * 32 + fsw;
#pragma unroll
    for (int ni = 0; ni < 8; ++ni)  boff[ni] = BM * 32 + (ni * 16 + fr) * 32 + fsw;

#define STAGE(kt, bsel) do {                                                   \
        const int _k = (kt) * 32;                                              \
        u16* _b = lds + (bsel) * BUFU;                                         \
        _Pragma("unroll")                                                      \
        for (int it = 0; it < AR; ++it)                                        \
            gl_lds16(gA + _k + (size_t)it * 32 * 1024, _b + dstA + it * 1024); \
        _Pragma("unroll")                                                      \
        for (int it = 0; it < 4; ++it)                                         \
            gl_lds16(gB + _k + (size_t)it * 32 * 1024, _b + dstB + it * 1024); \
    } while (0)

#define VM_WAIT_STEADY() do {                                                  \
        if (MODE == 0) asm volatile("s_waitcnt vmcnt(8)" ::: "memory");        \
        else           asm volatile("s_waitcnt vmcnt(6)" ::: "memory");        \
    } while (0)

    // prologue: tiles 0,1; wait tile0 landed (tile1's loads stay in flight)
    STAGE(0, 0);
    STAGE(1, 1);
    VM_WAIT_STEADY();
    __builtin_amdgcn_sched_barrier(0);
    __builtin_amdgcn_s_barrier();

    f32x4 acc[MI][8] = {};
    int cb = 0, sb = 2;

    for (int t = 0; t < NT; ++t) {
        if (t + 2 < NT) STAGE(t + 2, sb);
        const u16* buf = lds + cb * BUFU;
        bf16x8 af[MI], bfv[8];
#pragma unroll
        for (int mi = 0; mi < MI; ++mi)
            af[mi] = *reinterpret_cast<const bf16x8*>(&buf[aoff[mi]]);
#pragma unroll
        for (int ni = 0; ni < 8; ++ni)
            bfv[ni] = *reinterpret_cast<const bf16x8*>(&buf[boff[ni]]);
        __builtin_amdgcn_s_setprio(1);
#pragma unroll
        for (int mi = 0; mi < MI; ++mi)
#pragma unroll
            for (int ni = 0; ni < 8; ++ni)
                acc[mi][ni] = __builtin_amdgcn_mfma_f32_16x16x32_bf16(
                    af[mi], bfv[ni], acc[mi][ni], 0, 0, 0);
        __builtin_amdgcn_s_setprio(0);
        if (t < NT - 2)       VM_WAIT_STEADY();
        else if (t == NT - 2) asm volatile("s_waitcnt vmcnt(0)" ::: "memory");
        __builtin_amdgcn_sched_barrier(0);
        __builtin_amdgcn_s_barrier();
        cb = (cb == 2) ? 0 : cb + 1;
        sb = (sb == 2) ? 0 : sb + 1;
    }
#undef STAGE
#undef VM_WAIT_STEADY

    if (MODE == 0) {
        const int seg = n0 >> 10;                          // 0=q 1=k 2=v
        const float* bp = (seg == 0) ? b0 : (seg == 1) ? b1 : b2;
#pragma unroll
        for (int mi = 0; mi < MI; ++mi)
#pragma unroll
            for (int ni = 0; ni < 8; ++ni) {
                const int nl    = (n0 & 1023) + ni * 16 + fr;
                const int mbase = m0 + wr + mi * 16 + fq * 4;
                const float bn  = bp[nl];
                float vr[4];
#pragma unroll
                for (int r = 0; r < 4; ++r) {
                    float v = acc[mi][ni][r] + bn;
                    if (seg < 2) v = (v > 0.f) ? (v + 1.f) : __expf(v);  // elu+1
                    vr[r] = v;
                }
                if (seg == 0) {
#pragma unroll
                    for (int r = 0; r < 4; ++r)
                        Qb[(size_t)(mbase + r) * 1024 + nl] = f2b(vr[r]);
                } else {
                    us4 pk;
#pragma unroll
                    for (int r = 0; r < 4; ++r) pk[r] = f2b(vr[r]);
                    const int bb = mbase >> 11, nt = mbase & 2047;
                    const int hh = nl >> 6,     dd = nl & 63;
                    u16* T = (seg == 1) ? KbT : VbT;
                    *reinterpret_cast<us4*>(
                        &T[((size_t)(bb * 16 + hh) * 64 + dd) * 2048 + nt]) = pk;
                    if (seg == 1) {
#pragma unroll
                        for (int r = 0; r < 4; ++r)
                            Kb[(size_t)(mbase + r) * 1024 + nl] = f2b(vr[r]);
                    }
                }
            }
    } else {
#pragma unroll
        for (int mi = 0; mi < MI; ++mi)
#pragma unroll
            for (int ni = 0; ni < 8; ++ni) {
                const int n     = n0 + ni * 16 + fr;
                const int mbase = m0 + wr + mi * 16 + fq * 4;
                const float bn  = b0[n];
#pragma unroll
                for (int r = 0; r < 4; ++r)
                    outF[(size_t)(mbase + r) * 1024 + n] = acc[mi][ni][r] + bn;
            }
    }
}

// ---------------- per-chunk KV^T = v^T @ k: KVT[de][dk], bf16 out ----------------
__global__ __launch_bounds__(64)
void chunk_kv_kernel(const u16* __restrict__ KbT, const u16* __restrict__ VbT,
                     u16* __restrict__ KVT)
{
    const int blk = blockIdx.x;          // bh*NC + c
    const int bh = blk >> 5, c = blk & 31;
    const int lane = threadIdx.x;
    const int fr = lane & 15, fq = lane >> 4, fk = fq * 8;
    const u16* kt = KbT + (size_t)bh * 64 * 2048;
    const u16* vt = VbT + (size_t)bh * 64 * 2048;

    bf16x8 a[4][2], b[4][2];             // a = V rows (de), b = K rows (dk)
#pragma unroll
    for (int mi = 0; mi < 4; ++mi)
#pragma unroll
        for (int kh = 0; kh < 2; ++kh)
            a[mi][kh] = *reinterpret_cast<const bf16x8*>(
                &vt[(size_t)(mi * 16 + fr) * 2048 + c * 64 + kh * 32 + fk]);
#pragma unroll
    for (int ni = 0; ni < 4; ++ni)
#pragma unroll
        for (int kh = 0; kh < 2; ++kh)
            b[ni][kh] = *reinterpret_cast<const bf16x8*>(
                &kt[(size_t)(ni * 16 + fr) * 2048 + c * 64 + kh * 32 + fk]);

    f32x4 acc[4][4] = {};
    __builtin_amdgcn_s_setprio(1);
#pragma unroll
    for (int mi = 0; mi < 4; ++mi)
#pragma unroll
        for (int ni = 0; ni < 4; ++ni)
#pragma unroll
            for (int kh = 0; kh < 2; ++kh)
                acc[mi][ni] = __builtin_amdgcn_mfma_f32_16x16x32_bf16(
                    a[mi][kh], b[ni][kh], acc[mi][ni], 0, 0, 0);
    __builtin_amdgcn_s_setprio(0);

    u16* out = KVT + (size_t)blk * 4096;   // [de][dk] bf16
#pragma unroll
    for (int mi = 0; mi < 4; ++mi)
#pragma unroll
        for (int ni = 0; ni < 4; ++ni)
#pragma unroll
            for (int r = 0; r < 4; ++r)
                out[(mi * 16 + fq * 4 + r) * 64 + ni * 16 + fr] = f2b(acc[mi][ni][r]);
}

// ---------------- elementwise exclusive scan over chunks (bf16 in/out) ----------------
__global__ __launch_bounds__(256)
void scan_kernel(const u16* __restrict__ KVT, u16* __restrict__ STb)
{
    const int bh = blockIdx.x >> 4, sl = blockIdx.x & 15;
    const int el = sl * 256 + threadIdx.x;              // element of [de][dk]
    const u16* src = KVT + (size_t)bh * NC * 4096 + el;
    u16*      dst  = STb + (size_t)bh * NC * 4096 + el;
    float run = 0.f;
#pragma unroll 4
    for (int c = 0; c < NC; ++c) {
        dst[(size_t)c * 4096] = f2b(run);               // exclusive prefix
        run += b2f(src[(size_t)c * 4096]);
    }
}

// ---------------- per-chunk attention output ----------------
__global__ __launch_bounds__(64)
void attn_kernel(const u16* __restrict__ Qb, const u16* __restrict__ Kb,
                 const u16* __restrict__ VbT, const u16* __restrict__ STb,
                 u16* __restrict__ Ob)
{
    __shared__ u16 P[64 * 72];   // stride 72 u16 = 144B: 16B-aligned, 2-way banks
    const int blk = blockIdx.x;
    const int bh = blk >> 5, c = blk & 31;
    const int b = bh >> 4, h = bh & 15;
    const int lane = threadIdx.x;
    const int fr = lane & 15, fq = lane >> 4, fk = fq * 8;
    const int tok0 = b * 2048 + c * 64;

    bf16x8 qa[4][2];
#pragma unroll
    for (int mi = 0; mi < 4; ++mi)
#pragma unroll
        for (int kh = 0; kh < 2; ++kh)
            qa[mi][kh] = *reinterpret_cast<const bf16x8*>(
                &Qb[(size_t)(tok0 + mi * 16 + fr) * 1024 + h * 64 + kh * 32 + fk]);

    // P = causal-mask(q @ k^T) -> LDS bf16
    {
        bf16x8 kb[4][2];
#pragma unroll
        for (int si = 0; si < 4; ++si)
#pragma unroll
            for (int kh = 0; kh < 2; ++kh)
                kb[si][kh] = *reinterpret_cast<const bf16x8*>(
                    &Kb[(size_t)(tok0 + si * 16 + fr) * 1024 + h * 64 + kh * 32 + fk]);
        f32x4 p[4][4] = {};
        __builtin_amdgcn_s_setprio(1);
#pragma unroll
        for (int mi = 0; mi < 4; ++mi)
#pragma unroll
            for (int si = 0; si < 4; ++si)
#pragma unroll
                for (int kh = 0; kh < 2; ++kh)
                    p[mi][si] = __builtin_amdgcn_mfma_f32_16x16x32_bf16(
                        qa[mi][kh], kb[si][kh], p[mi][si], 0, 0, 0);
        __builtin_amdgcn_s_setprio(0);
#pragma unroll
        for (int mi = 0; mi < 4; ++mi)
#pragma unroll
            for (int si = 0; si < 4; ++si)
#pragma unroll
                for (int r = 0; r < 4; ++r) {
                    int t = mi * 16 + fq * 4 + r;
                    int s = si * 16 + fr;
                    float v = (s <= t) ? p[mi][si][r] : 0.0f;
                    P[t * 72 + s] = f2b(v);
                }
    }
    __syncthreads();

    f32x4 acc[4][4] = {};
    // acc = q @ ST   (STb[de][dk], dk-contiguous)
    {
        const u16* st = STb + (size_t)blk * 4096;
        bf16x8 sb[4][2];
#pragma unroll
        for (int ni = 0; ni < 4; ++ni)
#pragma unroll
            for (int kh = 0; kh < 2; ++kh)
                sb[ni][kh] = *reinterpret_cast<const bf16x8*>(
                    &st[(ni * 16 + fr) * 64 + kh * 32 + fk]);
        __builtin_amdgcn_s_setprio(1);
#pragma unroll
        for (int mi = 0; mi < 4; ++mi)
#pragma unroll
            for (int ni = 0; ni < 4; ++ni)
#pragma unroll
                for (int kh = 0; kh < 2; ++kh)
                    acc[mi][ni] = __builtin_amdgcn_mfma_f32_16x16x32_bf16(
                        qa[mi][kh], sb[ni][kh], acc[mi][ni], 0, 0, 0);
        __builtin_amdgcn_s_setprio(0);
    }
    // acc += P @ v
    {
        const u16* vt = VbT + (size_t)bh * 64 * 2048;
#pragma unroll
        for (int sh = 0; sh < 2; ++sh) {
            bf16x8 pa[4], vb[4];
#pragma unroll
            for (int mi = 0; mi < 4; ++mi)
                pa[mi] = *reinterpret_cast<const bf16x8*>(
                    &P[(mi * 16 + fr) * 72 + sh * 32 + fk]);
#pragma unroll
            for (int ni = 0; ni < 4; ++ni)
                vb[ni] = *reinterpret_cast<const bf16x8*>(
                    &vt[(size_t)(ni * 16 + fr) * 2048 + c * 64 + sh * 32 + fk]);
            __builtin_amdgcn_s_setprio(1);
#pragma unroll
            for (int mi = 0; mi < 4; ++mi)
#pragma unroll
                for (int ni = 0; ni < 4; ++ni)
                    acc[mi][ni] = __builtin_amdgcn_mfma_f32_16x16x32_bf16(
                        pa[mi], vb[ni], acc[mi][ni], 0, 0, 0);
            __builtin_amdgcn_s_setprio(0);
        }
    }
    // write token-major bf16 O
#pragma unroll
    for (int mi = 0; mi < 4; ++mi)
#pragma unroll
        for (int ni = 0; ni < 4; ++ni)
#pragma unroll
            for (int r = 0; r < 4; ++r) {
                int t = tok0 + mi * 16 + fq * 4 + r;
                int n = h * 64 + ni * 16 + fr;
                Ob[(size_t)t * 1024 + n] = f2b(acc[mi][ni][r]);
            }
}

extern "C" void kernel_launch(void* const* d_in, const int* in_sizes, int n_in,
                              void* d_out, int out_size, void* d_ws, size_t ws_size,
                              hipStream_t stream)
{
    (void)in_sizes; (void)n_in; (void)out_size; (void)ws_size;
    const float* x  = (const float*)d_in[0];
    const float* Wq = (const float*)d_in[1];
    const float* bq = (const float*)d_in[2];
    const float* Wk = (const float*)d_in[3];
    const float* bk = (const float*)d_in[4];
    const float* Wv = (const float*)d_in[5];
    const float* bv = (const float*)d_in[6];
    const float* Wo = (const float*)d_in[7];
    const float* bo = (const float*)d_in[8];
    float* out = (float*)d_out;

    char* ws = (char*)d_ws;
    constexpr size_t SZ_ME = (size_t)Mq * Eq * 2;        // 8 MB
    u16*   Qb  = (u16*)  (ws + 0 * SZ_ME);
    u16*   Kb  = (u16*)  (ws + 1 * SZ_ME);
    u16*   KbT = (u16*)  (ws + 2 * SZ_ME);
    u16*   VbT = (u16*)  (ws + 3 * SZ_ME);
    u16*   Ob  = (u16*)  (ws + 4 * SZ_ME);
    u16*   KVT = (u16*)  (ws + 5 * SZ_ME);               // 8 MB bf16
    u16*   STb = (u16*)  (ws + 6 * SZ_ME);
    u16*   Xb  = (u16*)  (ws + 7 * SZ_ME);
    u16*   Wb0 = (u16*)  (ws + 8 * SZ_ME);               // [Wq|Wk|Wv|Wo] bf16
    u16* Wqkvb = Wb0;
    u16* Wob   = Wb0 + (size_t)3 * Eq * Eq;

    // 1) all bf16 conversions, one launch
    cvt_all_kernel<<<dim3(8192), dim3(256), 0, stream>>>(x, Wq, Wk, Wv, Wo, Xb, Wb0);

    // 2) fused QKV projection (M=4096, N=3072): ring GEMM, 768 blocks (3/CU)
    gemm_ring<0><<<dim3(768), dim3(128), 0, stream>>>(
        Xb, Wqkvb, bq, bk, bv, Qb, Kb, KbT, VbT, nullptr);

    // 3) attention
    chunk_kv_kernel<<<dim3(BH * NC), dim3(64), 0, stream>>>(KbT, VbT, KVT);
    scan_kernel<<<dim3(BH * 16), dim3(256), 0, stream>>>(KVT, STb);
    attn_kernel<<<dim3(BH * NC), dim3(64), 0, stream>>>(Qb, Kb, VbT, STb, Ob);

    // 4) output projection (M=4096, N=1024): ring GEMM, 512 blocks
    gemm_ring<1><<<dim3(512), dim3(128), 0, stream>>>(
        Ob, Wob, bo, nullptr, nullptr, nullptr, nullptr, nullptr, nullptr, out);
}